// Round 1
// baseline (160.899 us; speedup 1.0000x reference)
//
#include <hip/hip_runtime.h>
#include <hip/hip_bf16.h>

#define Hh 96
#define Ww 128
#define Cc 21
#define Nn (Hh * Ww)      // 12288
#define RAD 20            // exp(-d^2/18) < 3e-10 beyond d=20

// ---------------------------------------------------------------------------
// Kernel A: precompute M = compat @ (Ws + Wb), and full-width norm factors
// nx[x] = sum_{x'} exp(-(x-x')^2/18), ny[y] likewise (norm_s = nx*ny exactly).
// ---------------------------------------------------------------------------
__global__ __launch_bounds__(256) void precompute_k(
    const float* __restrict__ Ws, const float* __restrict__ Wb,
    const float* __restrict__ compat,
    float* __restrict__ M, float* __restrict__ nx, float* __restrict__ ny) {
  const int tid = threadIdx.x;
  for (int i = tid; i < Cc * Cc; i += 256) {
    int a = i / Cc, b = i % Cc;
    float acc = 0.f;
    #pragma unroll
    for (int k = 0; k < Cc; ++k)
      acc += compat[a * Cc + k] * (Ws[k * Cc + b] + Wb[k * Cc + b]);
    M[i] = acc;
  }
  for (int x = tid; x < Ww; x += 256) {
    float s = 0.f;
    for (int xp = 0; xp < Ww; ++xp) {
      float d = (float)(x - xp);
      s += __expf(d * d * (-1.f / 18.f));
    }
    nx[x] = s;
  }
  for (int y = tid; y < Hh; y += 256) {
    float s = 0.f;
    for (int yp = 0; yp < Hh; ++yp) {
      float d = (float)(y - yp);
      s += __expf(d * d * (-1.f / 18.f));
    }
    ny[y] = s;
  }
}

// ---------------------------------------------------------------------------
// Kernel T: unaries NHWC -> channels-first [C][N]
// ---------------------------------------------------------------------------
__global__ __launch_bounds__(256) void transpose_u_k(
    const float* __restrict__ u, float* __restrict__ u_t) {
  int n = blockIdx.x * 256 + threadIdx.x;
  if (n < Nn) {
    #pragma unroll
    for (int c = 0; c < Cc; ++c) u_t[c * Nn + n] = u[n * Cc + c];
  }
}

// ---------------------------------------------------------------------------
// Kernel B: per image row h — softmax over classes, then horizontal Gaussian
// blur (radius RAD, weights in registers, fully unrolled, float4 LDS reads).
// qin is [C][N]; t out is [C][N].
// ---------------------------------------------------------------------------
__global__ __launch_bounds__(256) void softmax_blur_h_k(
    const float* __restrict__ qin, float* __restrict__ t) {
  const int h = blockIdx.x;
  const int tid = threadIdx.x;
  // padded row: 20 guard | 128 data | 20 guard = 168 floats per channel
  __shared__ __align__(16) float p_pad[Cc * 168];

  float w[RAD + 1];
  #pragma unroll
  for (int d = 0; d <= RAD; ++d)
    w[d] = __expf((float)(d * d) * (-1.f / 18.f));

  // zero guards
  for (int i = tid; i < Cc * 2 * RAD; i += 256) {
    int r = i / (2 * RAD), g = i % (2 * RAD);
    p_pad[r * 168 + (g < RAD ? g : (Ww + g))] = 0.f;
  }

  // softmax for pixel (h, x=tid)
  if (tid < Ww) {
    float v[Cc];
    float m = -1e30f;
    #pragma unroll
    for (int c = 0; c < Cc; ++c) {
      v[c] = qin[c * Nn + h * Ww + tid];
      m = fmaxf(m, v[c]);
    }
    float s = 0.f;
    #pragma unroll
    for (int c = 0; c < Cc; ++c) { v[c] = __expf(v[c] - m); s += v[c]; }
    float inv = 1.f / s;
    #pragma unroll
    for (int c = 0; c < Cc; ++c) p_pad[c * 168 + RAD + tid] = v[c] * inv;
  }
  __syncthreads();

  // blur: 21 channels x 32 quads of x (4 outputs per task)
  for (int i = tid; i < Cc * 32; i += 256) {
    int c = i >> 5, xq = i & 31;
    int x0 = xq * 4;
    const float* row = &p_pad[c * 168];
    float acc[4] = {0.f, 0.f, 0.f, 0.f};
    #pragma unroll
    for (int j = 0; j < 11; ++j) {
      float4 pv4 = *(const float4*)&row[x0 + 4 * j];
      float pv[4] = {pv4.x, pv4.y, pv4.z, pv4.w};
      #pragma unroll
      for (int k = 0; k < 4; ++k) {
        #pragma unroll
        for (int o = 0; o < 4; ++o) {
          int d = 4 * j + k - RAD - o;   // compile-time after unroll
          int ad = d < 0 ? -d : d;
          if (ad <= RAD) acc[o] += w[ad] * pv[k];
        }
      }
    }
    float4 res = {acc[0], acc[1], acc[2], acc[3]};
    *(float4*)&t[c * Nn + h * Ww + x0] = res;
  }
}

// ---------------------------------------------------------------------------
// Kernel C: per image column x — vertical blur, normalize by nx*ny, apply M,
// q_new = u - M @ s. On the last iteration writes the (1,W,H,C) output.
// ---------------------------------------------------------------------------
__global__ __launch_bounds__(256) void blur_v_update_k(
    const float* __restrict__ t, const float* __restrict__ u_t,
    const float* __restrict__ Mg, const float* __restrict__ nxg,
    const float* __restrict__ nyg,
    float* __restrict__ qout, float* __restrict__ outp, int last) {
  const int x = blockIdx.x;
  const int tid = threadIdx.x;
  // padded column: 20 | 96 | 20 = 136 floats per channel
  __shared__ __align__(16) float t_pad[Cc * 136];
  __shared__ __align__(16) float s_ld[Cc * 96];
  __shared__ float M_ld[Cc * Cc];
  __shared__ float ny_ld[Hh];

  float w[RAD + 1];
  #pragma unroll
  for (int d = 0; d <= RAD; ++d)
    w[d] = __expf((float)(d * d) * (-1.f / 18.f));

  for (int i = tid; i < Cc * 2 * RAD; i += 256) {
    int r = i / (2 * RAD), g = i % (2 * RAD);
    t_pad[r * 136 + (g < RAD ? g : (Hh + g))] = 0.f;
  }
  for (int i = tid; i < Cc * Cc; i += 256) M_ld[i] = Mg[i];
  if (tid < Hh) ny_ld[tid] = nyg[tid];
  const float nxv = nxg[x];

  for (int i = tid; i < Cc * Hh; i += 256) {
    int c = i / Hh, hh = i % Hh;
    t_pad[c * 136 + RAD + hh] = t[c * Nn + hh * Ww + x];
  }
  __syncthreads();

  // vertical blur + normalization: 21 channels x 24 quads of h
  for (int i = tid; i < Cc * 24; i += 256) {
    int c = i / 24, hq = i % 24;
    int h0 = hq * 4;
    const float* col = &t_pad[c * 136];
    float acc[4] = {0.f, 0.f, 0.f, 0.f};
    #pragma unroll
    for (int j = 0; j < 11; ++j) {
      float4 tv4 = *(const float4*)&col[h0 + 4 * j];
      float tv[4] = {tv4.x, tv4.y, tv4.z, tv4.w};
      #pragma unroll
      for (int k = 0; k < 4; ++k) {
        #pragma unroll
        for (int o = 0; o < 4; ++o) {
          int d = 4 * j + k - RAD - o;
          int ad = d < 0 ? -d : d;
          if (ad <= RAD) acc[o] += w[ad] * tv[k];
        }
      }
    }
    #pragma unroll
    for (int o = 0; o < 4; ++o)
      s_ld[c * 96 + h0 + o] = acc[o] / (nxv * ny_ld[h0 + o]);
  }
  __syncthreads();

  // q_new = u - M @ s ; write q (iters 0..3) or transposed output (iter 4)
  for (int i = tid; i < Cc * 24; i += 256) {
    int c = i / 24, hq = i % 24;
    int h0 = hq * 4;
    float acc[4] = {0.f, 0.f, 0.f, 0.f};
    #pragma unroll
    for (int b = 0; b < Cc; ++b) {
      float m = M_ld[c * Cc + b];
      float4 sv = *(const float4*)&s_ld[b * 96 + h0];
      acc[0] += m * sv.x;
      acc[1] += m * sv.y;
      acc[2] += m * sv.z;
      acc[3] += m * sv.w;
    }
    #pragma unroll
    for (int o = 0; o < 4; ++o) {
      int hh = h0 + o;
      float qn = u_t[c * Nn + hh * Ww + x] - acc[o];
      if (last) outp[(x * Hh + hh) * Cc + c] = qn;   // out[0][w][h][c]
      else qout[c * Nn + hh * Ww + x] = qn;
    }
  }
}

// ---------------------------------------------------------------------------
extern "C" void kernel_launch(void* const* d_in, const int* in_sizes, int n_in,
                              void* d_out, int out_size, void* d_ws, size_t ws_size,
                              hipStream_t stream) {
  const float* u      = (const float*)d_in[0];  // (1,H,W,C)
  // d_in[1] = rgb: DEAD (replicated source bug uses spatial_out twice)
  const float* Ws     = (const float*)d_in[2];
  const float* Wb     = (const float*)d_in[3];
  const float* compat = (const float*)d_in[4];
  float* out = (float*)d_out;

  float* ws   = (float*)d_ws;
  float* u_t  = ws;                 // [C][N]  258048
  float* q    = ws + 258048;        // [C][N]  258048
  float* t    = ws + 516096;        // [C][N]  258048
  float* M    = ws + 774144;        // 441
  float* nx   = ws + 774585;        // 128
  float* ny   = ws + 774713;        // 96

  precompute_k<<<1, 256, 0, stream>>>(Ws, Wb, compat, M, nx, ny);
  transpose_u_k<<<(Nn + 255) / 256, 256, 0, stream>>>(u, u_t);

  const float* qin = u_t;           // q_0 = u
  for (int it = 0; it < 5; ++it) {
    softmax_blur_h_k<<<Hh, 256, 0, stream>>>(qin, t);
    blur_v_update_k<<<Ww, 256, 0, stream>>>(t, u_t, M, nx, ny, q, out,
                                            it == 4 ? 1 : 0);
    qin = q;
  }
}